// Round 2
// baseline (6286.878 us; speedup 1.0000x reference)
//
#include <hip/hip_runtime.h>
#include <math.h>

// ============================================================================
// Persistent per-signal FFT ISTA solver, radix-8 edition.
//
// Math (identical to the verified radix-4 version):
//   u_{t+1} = u_t - 0.05*(I-P)*clamp20(u_t),  u_0 = 100*DCT(scatter(x[idxs]))
//   P*h = DCT2(mask(IDCT(h))) via FFT+ (DIF) then FFT- (DIT).
//   out = 0.01*IDCT(u_99 - 0.05*clamp20(u_99)).
//
// FFT decomposition: 2048 = 8*8*8*4. 256 threads/signal, 8 complex pts/thread.
//   DIF stages: S0 (stride 256, tw w2048^{t*b'}), S1 (stride 32, tw w256^{(t&31)c'}),
//               S2 (stride 4, tw w32^{(t&3)d'}), S3 (radix-4, consecutive).
//   Slot layout: p = 256b' + 32c' + 4d' + e'  holds Y[m], m = b' + 8c' + 64d' + 512e'.
//   DIT mirrors exactly (same thread/slot patterns, conjugate twiddles, reverse order).
//   S3 + mask + T0 fuse in registers (mask = per-thread 8-bit constant).
//   LDS XOR-swizzle  swz(p) = p ^ (((p>>5)&7)<<2)  makes S0/T3, S1/T2, S2/T1
//   accesses exactly 4 dword-accesses/bank (HW minimum); S3/T0 b128 is 2-way.
// 7 barriers/iter (was ~24), ~216 KB LDS traffic/signal/iter (was ~416 KB).
// ============================================================================

#define PIF 3.14159265358979323846f
#define C0F 0.022097086912079608f      // sqrt(1/2048)
#define TWOC0 0.044194173824159216f    // 2*sqrt(1/2048)
#define CNF 0.03125f                   // sqrt(2/2048)
#define SPW 3                          // signals per block; grid = 3072/3 = 1024

typedef float2 cf;

__device__ __forceinline__ int load_idx(const int* p, int j) {
    return (p[1] == 0) ? p[2 * j] : p[j];   // int64 (lo,0) pairs or int32
}
__device__ __forceinline__ int pinv(int m) {   // frequency -> slot
    return ((m & 7) << 8) | (((m >> 3) & 7) << 5) | (((m >> 6) & 7) << 2) | ((m >> 9) & 3);
}
__device__ __forceinline__ int permf(int p) {  // slot -> frequency
    return (p >> 8) | (((p >> 5) & 7) << 3) | (((p >> 2) & 7) << 6) | ((p & 3) << 9);
}
__device__ __forceinline__ float clamp20(float g) {
    return fminf(fmaxf(20.f * g, -1.f), 1.f);
}
__device__ __forceinline__ cf cadd(cf a, cf b) { return make_float2(a.x + b.x, a.y + b.y); }
__device__ __forceinline__ cf csub(cf a, cf b) { return make_float2(a.x - b.x, a.y - b.y); }
__device__ __forceinline__ cf cmul(cf a, cf b) {
    return make_float2(a.x * b.x - a.y * b.y, a.x * b.y + a.y * b.x);
}
__device__ __forceinline__ cf cmulc(cf a, cf b) {   // a * conj(b)
    return make_float2(a.x * b.x + a.y * b.y, a.y * b.x - a.x * b.y);
}
template <int S> __device__ __forceinline__ cf imul(cf z) {  // (S*i)*z
    return (S > 0) ? make_float2(-z.y, z.x) : make_float2(z.y, -z.x);
}

// In-place DFT-8: v[j] = sum_b v_in[b] * w8^{S*b*j}   (verified via delta traces)
template <int S>
__device__ __forceinline__ void dft8(cf* v) {
    const float R2 = 0.70710678118654752f;
    cf A0 = cadd(v[0], v[4]), D0 = csub(v[0], v[4]);
    cf A1 = cadd(v[1], v[5]), D1 = csub(v[1], v[5]);
    cf A2 = cadd(v[2], v[6]), D2 = csub(v[2], v[6]);
    cf A3 = cadd(v[3], v[7]), D3 = csub(v[3], v[7]);
    const cf w8  = make_float2(R2, (S > 0) ? R2 : -R2);    // w8^{S}
    const cf w83 = make_float2(-R2, (S > 0) ? R2 : -R2);   // w8^{3S}
    D1 = cmul(D1, w8);
    D2 = imul<S>(D2);
    D3 = cmul(D3, w83);
    cf E0 = cadd(A0, A2), E1 = csub(A0, A2);
    cf O0 = cadd(A1, A3), O1 = imul<S>(csub(A1, A3));
    cf F0 = cadd(D0, D2), F1 = csub(D0, D2);
    cf P0 = cadd(D1, D3), P1 = imul<S>(csub(D1, D3));
    v[0] = cadd(E0, O0); v[2] = cadd(E1, O1);
    v[4] = csub(E0, O0); v[6] = csub(E1, O1);
    v[1] = cadd(F0, P0); v[3] = cadd(F1, P1);
    v[5] = csub(F0, P0); v[7] = csub(F1, P1);
}

// In-place DFT-4: v[j] = sum_m v_in[m] * w4^{S*m*j}
template <int S>
__device__ __forceinline__ void dft4(cf* v) {
    cf E0 = cadd(v[0], v[2]), E1 = csub(v[0], v[2]);
    cf O0 = cadd(v[1], v[3]), O1 = imul<S>(csub(v[1], v[3]));
    v[0] = cadd(E0, O0); v[1] = cadd(E1, O1);
    v[2] = csub(E0, O0); v[3] = csub(E1, O1);
}

__device__ __forceinline__ void twpow(cf W, cf* w) {   // w[j-1] = W^j, j=1..7
    w[0] = W;
    w[1] = cmul(W, W);
    w[2] = cmul(w[1], W);
    w[3] = cmul(w[1], w[1]);
    w[4] = cmul(w[1], w[2]);
    w[5] = cmul(w[2], w[2]);
    w[6] = cmul(w[2], w[3]);
}

__global__ __launch_bounds__(256, 4) void ista_fft_kernel(
    const float* __restrict__ x, const int* __restrict__ idxs,
    float* __restrict__ out)
{
    __shared__ __align__(16) cf wk[2048];   // 16 KB, swizzled slot space
    __shared__ float g[2048];               // 8 KB  (u vector; reused for output)
    __shared__ unsigned mbm[64];            // slot-space measurement bitmask

    const int t = threadIdx.x;
    const int t5 = t >> 5;
    const int s1b = t & 31;
    const int s2k = t & 3, s2c = (t >> 2) & 7;
    const int tsw = t ^ (((t >> 5) & 7) << 2);   // swz(t) for stride-256 stages

    if (t < 64) mbm[t] = 0u;
    __syncthreads();

    // measurements j = t and t+256: x-index -> y-index -> slot
    const int mi0 = load_idx(idxs, t), mi1 = load_idx(idxs, t + 256);
    const int yd0 = (mi0 & 1) ? (2047 - (mi0 >> 1)) : (mi0 >> 1);
    const int yd1 = (mi1 & 1) ? (2047 - (mi1 >> 1)) : (mi1 >> 1);
    const int pm0 = pinv(yd0), pm1 = pinv(yd1);
    atomicOr(&mbm[pm0 >> 5], 1u << (pm0 & 31));
    atomicOr(&mbm[pm1 >> 5], 1u << (pm1 & 31));
    const int sl0 = pm0 ^ (((pm0 >> 5) & 7) << 2);   // swizzled scatter slots
    const int sl1 = pm1 ^ (((pm1 >> 5) & 7) << 2);
    __syncthreads();
    const unsigned msk = (mbm[t >> 2] >> ((t & 3) * 8)) & 0xffu;  // bits for slots 8t..8t+7

    // thread-invariant trig
    float s0a, c0a; sincosf(PIF * (float)t * (1.f / 4096.f), &s0a, &c0a);       // e^{i pi t/4096}
    float sww, cww; sincosf(2.f * PIF * (float)t   * (1.f / 2048.f), &sww, &cww); // w2048^t
    float soo, coo; sincosf(2.f * PIF * (float)s1b * (1.f / 256.f),  &soo, &coo); // w256^{t&31}
    float sll, cll; sincosf(2.f * PIF * (float)s2k * (1.f / 32.f),   &sll, &cll); // w32^{t&3}
    cf Wp[7], Op[7], Lp[7];
    twpow(make_float2(cww, sww), Wp);
    twpow(make_float2(coo, soo), Op);
    twpow(make_float2(cll, sll), Lp);

    const float CR[8] = {1.f, 0.98078528040323044913f, 0.92387953251128675613f,
                         0.83146961230254523708f, 0.70710678118654752440f,
                         0.55557023301960222474f, 0.38268343236508977173f,
                         0.19509032201612826785f};
    const float SR[8] = {0.f, 0.19509032201612826785f, 0.38268343236508977173f,
                         0.55557023301960222474f, 0.70710678118654752440f,
                         0.83146961230254523708f, 0.92387953251128675613f,
                         0.98078528040323044913f};

    // swizzled stage addresses (all verified 4-accesses/bank per instruction)
    auto addr1 = [&](int c) { return (s1b ^ (c << 2)) + 32 * c + 256 * t5; };
    auto addr2 = [&](int d) { return s2k + 4 * (d ^ s2c) + 32 * s2c + 256 * t5; };

    auto difmid = [&](auto addr, const cf* wp) {
        cf v[8];
#pragma unroll
        for (int j = 0; j < 8; ++j) v[j] = wk[addr(j)];
        dft8<1>(v);
#pragma unroll
        for (int j = 1; j < 8; ++j) v[j] = cmul(v[j], wp[j - 1]);
#pragma unroll
        for (int j = 0; j < 8; ++j) wk[addr(j)] = v[j];
    };
    auto ditmid = [&](auto addr, const cf* wp) {
        cf v[8];
#pragma unroll
        for (int j = 0; j < 8; ++j) v[j] = wk[addr(j)];
#pragma unroll
        for (int j = 1; j < 8; ++j) v[j] = cmulc(v[j], wp[j - 1]);
        dft8<-1>(v);
#pragma unroll
        for (int j = 0; j < 8; ++j) wk[addr(j)] = v[j];
    };

    // DIF head: V-build from g (+ VMODE nonlinearity) fused with S0
    auto headS0 = [&](bool fin) {
        cf v[8];
#pragma unroll
        for (int b = 0; b < 8; ++b) {
            const int k = t + 256 * b;
            const int kN = (2048 - k) & 2047;
            float gk = g[k], gN = g[kN];
            float hk, hN;
            if (fin) { hk = gk - 0.05f * clamp20(gk); hN = gN - 0.05f * clamp20(gN); }
            else     { hk = clamp20(gk);              hN = clamp20(gN); }
            const bool kz = (k == 0);
            float Xk = (kz ? TWOC0 : CNF) * hk;
            float XN = kz ? 0.f : CNF * hN;
            float cc = c0a * CR[b] - s0a * SR[b];   // cos(pi k/4096)
            float ss = s0a * CR[b] + c0a * SR[b];   // sin(pi k/4096)
            v[b] = make_float2(0.5f * (Xk * cc + XN * ss), 0.5f * (Xk * ss - XN * cc));
        }
        dft8<1>(v);
#pragma unroll
        for (int j = 1; j < 8; ++j) v[j] = cmul(v[j], Wp[j - 1]);
#pragma unroll
        for (int j = 0; j < 8; ++j) wk[tsw + 256 * j] = v[j];
    };

    // DIT tail: T3 fused with DCT-II epilogue + g update
    auto tailT3 = [&](bool init) {
        cf v[8];
#pragma unroll
        for (int j = 0; j < 8; ++j) v[j] = wk[tsw + 256 * j];
#pragma unroll
        for (int j = 1; j < 8; ++j) v[j] = cmulc(v[j], Wp[j - 1]);
        dft8<-1>(v);
#pragma unroll
        for (int j = 0; j < 8; ++j) {
            const int k = t + 256 * j;
            float cc = c0a * CR[j] - s0a * SR[j];
            float ss = s0a * CR[j] + c0a * SR[j];
            float Cv = v[j].x * cc + v[j].y * ss;
            float u = ((k == 0) ? C0F : CNF) * Cv;
            if (init) g[k] = u;
            else { float gk = g[k]; g[k] = gk + 0.05f * (u - clamp20(gk)); }
        }
    };

    auto quadload = [&](int a, cf* v) {
        float4 lo = *(const float4*)(&wk[a]);
        float4 hi = *(const float4*)(&wk[a + 2]);
        v[0] = make_float2(lo.x, lo.y); v[1] = make_float2(lo.z, lo.w);
        v[2] = make_float2(hi.x, hi.y); v[3] = make_float2(hi.z, hi.w);
    };
    auto quadstore = [&](int a, const cf* v) {
        *(float4*)(&wk[a])     = make_float4(v[0].x, v[0].y, v[1].x, v[1].y);
        *(float4*)(&wk[a + 2]) = make_float4(v[2].x, v[2].y, v[3].x, v[3].y);
    };

#pragma unroll 1
    for (int s = 0; s < SPW; ++s) {
        const int r = blockIdx.x * SPW + s;

        // ---- init: wk = scatter(100*x[r, idxs]) in swizzled slot space ----
#pragma unroll
        for (int j = 0; j < 8; ++j) wk[t + 256 * j] = make_float2(0.f, 0.f);
        __syncthreads();
        wk[sl0] = make_float2(100.f * x[(size_t)r * 2048 + mi0], 0.f);
        wk[sl1] = make_float2(100.f * x[(size_t)r * 2048 + mi1], 0.f);
        __syncthreads();
        // T0 (no mask needed — input already masked)
#pragma unroll
        for (int q = 0; q < 2; ++q) {
            const int pb = 8 * t + 4 * q;
            const int a = pb ^ (((pb >> 5) & 7) << 2);
            cf v[4]; quadload(a, v);
            dft4<-1>(v);
            quadstore(a, v);
        }
        __syncthreads();
        ditmid(addr2, Lp); __syncthreads();   // T1
        ditmid(addr1, Op); __syncthreads();   // T2
        tailT3(true);      __syncthreads();   // g = u0 = A^T b

        // ---- 99 iterations ----
#pragma unroll 1
        for (int it = 0; it < 99; ++it) {
            headS0(false);     __syncthreads();  // S0 (reads g)
            difmid(addr1, Op); __syncthreads();  // S1
            difmid(addr2, Lp); __syncthreads();  // S2
#pragma unroll
            for (int q = 0; q < 2; ++q) {        // S3 + mask + T0, in registers
                const int pb = 8 * t + 4 * q;
                const int a = pb ^ (((pb >> 5) & 7) << 2);
                cf v[4]; quadload(a, v);
                dft4<1>(v);
#pragma unroll
                for (int e = 0; e < 4; ++e) {
                    float keep = (float)((msk >> (4 * q + e)) & 1u);
                    v[e] = make_float2(v[e].x * keep, 0.f);
                }
                dft4<-1>(v);
                quadstore(a, v);
            }
            __syncthreads();
            ditmid(addr2, Lp); __syncthreads();  // T1
            ditmid(addr1, Op); __syncthreads();  // T2
            tailT3(false);     __syncthreads();  // g update
        }

        // ---- final: out = 0.01 * IDCT(F') ----
        headS0(true);      __syncthreads();
        difmid(addr1, Op); __syncthreads();
        difmid(addr2, Lp); __syncthreads();
#pragma unroll
        for (int q = 0; q < 2; ++q) {            // S3 + reorder to x-order via g
            const int pb = 8 * t + 4 * q;
            const int a = pb ^ (((pb >> 5) & 7) << 2);
            cf v[4]; quadload(a, v);
            dft4<1>(v);
#pragma unroll
            for (int e = 0; e < 4; ++e) {
                const int m = permf(pb + e);
                const int i = (m < 1024) ? (m << 1) : (4095 - (m << 1));
                g[i] = 0.01f * v[e].x;
            }
        }
        __syncthreads();
#pragma unroll
        for (int j = 0; j < 8; ++j)
            out[(size_t)r * 2048 + t + 256 * j] = g[t + 256 * j];
        // wk/g hazards vs next signal are covered by the init-phase barriers
    }
}

extern "C" void kernel_launch(void* const* d_in, const int* in_sizes, int n_in,
                              void* d_out, int out_size, void* d_ws, size_t ws_size,
                              hipStream_t stream) {
    (void)in_sizes; (void)n_in; (void)out_size; (void)d_ws; (void)ws_size;
    const float* x = (const float*)d_in[0];
    const int* idxs = (const int*)d_in[1];
    ista_fft_kernel<<<dim3(3072 / SPW), dim3(256), 0, stream>>>(x, idxs, (float*)d_out);
}